// Round 2
// baseline (263.141 us; speedup 1.0000x reference)
//
#include <hip/hip_runtime.h>

#define B_ 8
#define L_ 4096
#define H_ 8
#define E_ 64
#define NEIGH_ 128
#define SPLITS_ 32
#define BQ 128        // queries per block
#define WIN 256       // key window per block
#define NT 10         // key tiles per wave (band needs 9; 10 for even pairing)
#define NP 5          // PV 32-key chunks per wave

typedef float f32x4 __attribute__((ext_vector_type(4)));
typedef __bf16 bf16x2 __attribute__((ext_vector_type(2)));
typedef __bf16 bf16x8 __attribute__((ext_vector_type(8)));
typedef unsigned short u16x8 __attribute__((ext_vector_type(8)));
typedef unsigned int u32;
typedef u32 u32x4 __attribute__((ext_vector_type(4)));

// compiler lowers paired casts to v_cvt_pk_bf16_f32 (RNE), 1 op / 2 elems
__device__ inline u32 pack2(float a, float b) {
  bf16x2 t = {(__bf16)a, (__bf16)b};
  return __builtin_bit_cast(u32, t);
}
__device__ inline bf16x8 cvt8(const float4& x, const float4& y) {
  bf16x8 r = {(__bf16)x.x, (__bf16)x.y, (__bf16)x.z, (__bf16)x.w,
              (__bf16)y.x, (__bf16)y.y, (__bf16)y.z, (__bf16)y.w};
  return r;
}

// S^T formulation: S^T[key][q] = K·Q^T. C-layout: q = lane&15, key = quad*4+reg.
// K is NOT staged in LDS: its reuse is only ~5x/block and the 64KB window is
// L2-resident (XCD remap keeps neighbors on one XCD). A-fragments load straight
// from global f32 (128B/row segments), converted in-register. This cuts LDS to
// 32KB (V only) -> 4 blocks/CU, and leaves ONE barrier, placed after softmax,
// so V-staging latency hides under the S phase.
__global__ __launch_bounds__(512, 6) void la_kernel(
    const float* __restrict__ Q, const float* __restrict__ K,
    const float* __restrict__ V, float* __restrict__ out) {
  // XCD-aware remap: linear dispatch id round-robins XCDs (lid % 8).
  // Each XCD gets 256 CONSECUTIVE logical blocks. Bijective: 2048 = 8*256.
  const int lid = blockIdx.x + SPLITS_ * (blockIdx.y + H_ * blockIdx.z);
  const int logical = (lid & 7) * 256 + (lid >> 3);
  const int j = logical & (SPLITS_ - 1);
  const int h = (logical >> 5) & (H_ - 1);
  const int b = logical >> 8;
  const int t = threadIdx.x;

  __shared__ u32 Vs32[E_ * (WIN / 2)];  // 32,768 B VsT [e][key], XOR-swizzled 8-key groups

  const int q0 = j * BQ;
  const int g0 = q0 - NEIGH_;   // global key index of window position 0

  // ---- stage V transposed [e][key], pair-packed b32 writes (issue first: its
  // latency + LDS writes hide under the whole S phase; barrier is after softmax)
  for (int i = 0; i < 4; ++i) {
    int idx = t + i * 512;                 // 0..2047
    int kp = idx >> 4, c4 = idx & 15;      // key pair 0..127, col group 0..15
    int k0g = g0 + 2 * kp, k1g = k0g + 1;
    k0g = k0g < 0 ? 0 : k0g; k1g = k1g < 0 ? 0 : k1g;
    const float4 v0 = *(const float4*)(V + ((((size_t)b * L_) + k0g) * H_ + h) * E_ + c4 * 4);
    const float4 v1 = *(const float4*)(V + ((((size_t)b * L_) + k1g) * H_ + h) * E_ + c4 * 4);
    int g = kp >> 2;                       // 8-key group 0..31
    int ko = kp & 3;                       // u32 offset within group (2 keys per u32)
    const float a0[4] = {v0.x, v0.y, v0.z, v0.w};
    const float a1[4] = {v1.x, v1.y, v1.z, v1.w};
#pragma unroll
    for (int w = 0; w < 4; ++w) {
      int e = c4 * 4 + w;
      int gs = g ^ (e & 31);               // swizzled group
      Vs32[e * 128 + gs * 4 + ko] = pack2(a0[w], a1[w]);
    }
  }

  const int wv = t >> 6, lane = t & 63;
  const int l15 = lane & 15, quad = lane >> 4;
  const int r0 = wv * 16;    // wave's first query row (16 per wave)
  const int lq = r0 + l15;   // this lane's query (local index 0..127)
  const int start = wv & ~1; // first key tile this wave needs (even-aligned)
  const int ks0 = start >> 1;  // first 32-key chunk for PV

  // ---- Q B-fragment direct from global: B[k=e][n=q] ----
  bf16x8 qfrag[2];
  {
    const float* qrow = Q + ((((size_t)b * L_) + q0 + lq) * H_ + h) * E_;
#pragma unroll
    for (int ks = 0; ks < 2; ++ks) {
      const float4 x = *(const float4*)(qrow + ks * 32 + quad * 8);
      const float4 y = *(const float4*)(qrow + ks * 32 + quad * 8 + 4);
      qfrag[ks] = cvt8(x, y);
    }
  }

  // ---- S^T = K Q^T over NT=10 tiles, K A-fragments straight from global ----
  f32x4 S[NT];
#pragma unroll
  for (int si = 0; si < NT; ++si) S[si] = (f32x4){0.f, 0.f, 0.f, 0.f};
#pragma unroll
  for (int si = 0; si < NT; ++si) {
    int g = g0 + (start + si) * 16 + l15;
    g = g < 0 ? 0 : g;                     // clamp (masked later); upper bound never exceeds L-1
    const float* krow = K + ((((size_t)b * L_) + g) * H_ + h) * E_;
    const float4 x0 = *(const float4*)(krow + quad * 8);
    const float4 y0 = *(const float4*)(krow + quad * 8 + 4);
    const float4 x1 = *(const float4*)(krow + 32 + quad * 8);
    const float4 y1 = *(const float4*)(krow + 32 + quad * 8 + 4);
    S[si] = __builtin_amdgcn_mfma_f32_16x16x32_bf16(cvt8(x0, y0), qfrag[0], S[si], 0, 0, 0);
    S[si] = __builtin_amdgcn_mfma_f32_16x16x32_bf16(cvt8(x1, y1), qfrag[1], S[si], 0, 0, 0);
  }

  // ---- scale + mask + row max (one query row per lane: q = l15) ----
  float m = -1e30f;
#pragma unroll
  for (int si = 0; si < NT; ++si) {
#pragma unroll
    for (int r = 0; r < 4; ++r) {
      int key = (start + si) * 16 + quad * 4 + r;
      float s = S[si][r] * 0.125f;
      bool valid = (key > lq) & (key <= lq + NEIGH_) & (g0 + key >= 0);
      s = valid ? s : -1e30f;
      S[si][r] = s;
      m = fmaxf(m, s);
    }
  }
  m = fmaxf(m, __shfl_xor(m, 16));
  m = fmaxf(m, __shfl_xor(m, 32));

  // ---- exp + row sum; pack P to bf16 pairs (C-layout regs (0,1),(2,3)) ----
  float lsum = 0.f;
  u32 pk[NT][2];
#pragma unroll
  for (int si = 0; si < NT; ++si) {
    float p0 = __expf(S[si][0] - m);
    float p1 = __expf(S[si][1] - m);
    float p2 = __expf(S[si][2] - m);
    float p3 = __expf(S[si][3] - m);
    lsum += (p0 + p1) + (p2 + p3);
    pk[si][0] = pack2(p0, p1);
    pk[si][1] = pack2(p2, p3);
  }
  lsum += __shfl_xor(lsum, 16);
  lsum += __shfl_xor(lsum, 32);
  const float inv = 1.0f / lsum;

  __syncthreads();   // the ONLY barrier: Vs must be complete before PV

  // ---- O = P V : A = P via register transpose (bpermute), B = VsT swizzled ----
  f32x4 O[4];
#pragma unroll
  for (int et = 0; et < 4; ++et) O[et] = (f32x4){0.f, 0.f, 0.f, 0.f};
  const int srcBase = 16 * ((quad & 1) * 2) + l15;   // + 16*(k>>1)
  const bool hiTile = (quad >> 1) != 0;
#pragma unroll
  for (int pi = 0; pi < NP; ++pi) {
    const int ap = ks0 + pi;               // absolute 32-key chunk
    u32 a32[4];
#pragma unroll
    for (int k = 0; k < 4; ++k) {
      int src = srcBase + 16 * (k >> 1);
      u32 u0 = (u32)__shfl((int)pk[2 * pi][k & 1], src);
      u32 u1 = (u32)__shfl((int)pk[2 * pi + 1][k & 1], src);
      a32[k] = hiTile ? u1 : u0;
    }
    bf16x8 afrag = __builtin_bit_cast(bf16x8,
        (u32x4){a32[0], a32[1], a32[2], a32[3]});
    __builtin_amdgcn_s_setprio(1);
#pragma unroll
    for (int et = 0; et < 4; ++et) {
      int e = et * 16 + l15;
      int gs = (ap * 4 + quad) ^ (e & 31);
      bf16x8 bfrag = __builtin_bit_cast(bf16x8,
          *(const u16x8*)((const unsigned short*)Vs32 + e * 256 + gs * 8));
      O[et] = __builtin_amdgcn_mfma_f32_16x16x32_bf16(afrag, bfrag, O[et], 0, 0, 0);
    }
    __builtin_amdgcn_s_setprio(0);
  }

  // ---- store: O C-layout row = q = quad*4+r, col = e = et*16+l15 ----
  float invq[4];
#pragma unroll
  for (int r = 0; r < 4; ++r) invq[r] = __shfl(inv, quad * 4 + r);
#pragma unroll
  for (int et = 0; et < 4; ++et)
#pragma unroll
    for (int r = 0; r < 4; ++r) {
      int row = r0 + quad * 4 + r;
      out[((((size_t)b * L_) + q0 + row) * H_ + h) * E_ + et * 16 + l15] = O[et][r] * invq[r];
    }
}

extern "C" void kernel_launch(void* const* d_in, const int* in_sizes, int n_in,
                              void* d_out, int out_size, void* d_ws, size_t ws_size,
                              hipStream_t stream) {
  const float* q = (const float*)d_in[0];
  const float* k = (const float*)d_in[1];
  const float* v = (const float*)d_in[2];
  float* o = (float*)d_out;
  dim3 grid(SPLITS_, H_, B_);   // 2048 blocks
  la_kernel<<<grid, 512, 0, stream>>>(q, k, v, o);
}

// Round 3
// 223.767 us; speedup vs baseline: 1.1760x; 1.1760x over previous
//
#include <hip/hip_runtime.h>

#define B_ 8
#define L_ 4096
#define H_ 8
#define E_ 64
#define NEIGH_ 128
#define SPLITS_ 32
#define BQ 128        // queries per block
#define WIN 256       // key window per block
#define KPAD 72       // 64 + 8 pad (bf16 elems) for Ks rows
#define NT 10         // key tiles per wave (band needs 9; 10 for even pairing)
#define NP 5          // PV 32-key chunks per wave
#define SCALE_LOG2E 0.18033688011112042f   // (1/sqrt(E)) * log2(e); softmax done in exp2 domain

typedef float f32x4 __attribute__((ext_vector_type(4)));
typedef __bf16 bf16x2 __attribute__((ext_vector_type(2)));
typedef __bf16 bf16x8 __attribute__((ext_vector_type(8)));
typedef unsigned short u16x8 __attribute__((ext_vector_type(8)));
typedef unsigned int u32;
typedef u32 u32x2 __attribute__((ext_vector_type(2)));
typedef u32 u32x4 __attribute__((ext_vector_type(4)));

// compiler lowers paired casts to v_cvt_pk_bf16_f32 (RNE), 1 op / 2 elems
__device__ inline u32 pack2(float a, float b) {
  bf16x2 t = {(__bf16)a, (__bf16)b};
  return __builtin_bit_cast(u32, t);
}

// S^T formulation: S^T[key][q] = K·Q^T. C-layout: q = lane&15, key = quad*4+reg.
// LDS is ONE 36,864 B buffer time-shared: K (bf16, padded rows) during the S
// phase, then V^T (bf16 pairs, XOR-swizzled) for PV. 3 barriers. V global loads
// are ISSUED before barrier 2 (T14 issue-early / write-late) so HBM latency
// hides under the barrier wait; the restage stall is covered by ~3 blocks/CU
// (vs 2 at the old 69,632 B footprint).
__global__ __launch_bounds__(512, 6) void la_kernel(
    const float* __restrict__ Q, const float* __restrict__ K,
    const float* __restrict__ V, float* __restrict__ out) {
  // XCD-aware remap: linear dispatch id round-robins XCDs (lid % 8).
  // Each XCD gets 256 CONSECUTIVE logical blocks. Bijective: 2048 = 8*256.
  const int lid = blockIdx.x + SPLITS_ * (blockIdx.y + H_ * blockIdx.z);
  const int logical = (lid & 7) * 256 + (lid >> 3);
  const int j = logical & (SPLITS_ - 1);
  const int h = (logical >> 5) & (H_ - 1);
  const int b = logical >> 8;
  const int t = threadIdx.x;

  __shared__ __align__(16) unsigned char smem[WIN * KPAD * 2];  // 36,864 B
  unsigned short* Ks = (unsigned short*)smem;       // phase A: K [256][72] bf16
  u32* Vs32 = (u32*)smem;                           // phase B: V^T [64][128] key-pairs

  const int q0 = j * BQ;
  const int g0 = q0 - NEIGH_;   // global key index of window position 0

  // ---- stage K (coalesced float4 -> bf16, packed converts) ----
#pragma unroll
  for (int i = 0; i < 8; ++i) {
    int idx = t + i * 512;                 // 0..4095
    int km = idx >> 4, c4 = idx & 15;
    int g = g0 + km; g = g < 0 ? 0 : g;    // clamp (masked later)
    const float4 v = *(const float4*)(K + ((((size_t)b * L_) + g) * H_ + h) * E_ + c4 * 4);
    *(u32x2*)&Ks[km * KPAD + c4 * 4] = (u32x2){pack2(v.x, v.y), pack2(v.z, v.w)};
  }

  const int wv = t >> 6, lane = t & 63;
  const int l15 = lane & 15, quad = lane >> 4;
  const int r0 = wv * 16;    // wave's first query row (16 per wave)
  const int lq = r0 + l15;   // this lane's query (local index 0..127)
  const int start = wv & ~1; // first key tile this wave needs (even-aligned)
  const int ks0 = start >> 1;  // first 32-key chunk for PV

  // ---- Q B-fragment from global, PRE-SCALED by 1/sqrt(E)*log2(e) ----
  bf16x8 qfrag[2];
  {
    const float* qrow = Q + ((((size_t)b * L_) + q0 + lq) * H_ + h) * E_;
#pragma unroll
    for (int ks = 0; ks < 2; ++ks) {
      const float4 x = *(const float4*)(qrow + ks * 32 + quad * 8);
      const float4 y = *(const float4*)(qrow + ks * 32 + quad * 8 + 4);
      bf16x8 r = {(__bf16)(x.x * SCALE_LOG2E), (__bf16)(x.y * SCALE_LOG2E),
                  (__bf16)(x.z * SCALE_LOG2E), (__bf16)(x.w * SCALE_LOG2E),
                  (__bf16)(y.x * SCALE_LOG2E), (__bf16)(y.y * SCALE_LOG2E),
                  (__bf16)(y.z * SCALE_LOG2E), (__bf16)(y.w * SCALE_LOG2E)};
      qfrag[ks] = r;
    }
  }
  __syncthreads();   // barrier 1: Ks staged

  // ---- S^T = K Q^T over NT=10 tiles (scores already in exp2 domain) ----
  f32x4 S[NT];
#pragma unroll
  for (int si = 0; si < NT; ++si) S[si] = (f32x4){0.f, 0.f, 0.f, 0.f};
#pragma unroll
  for (int ks = 0; ks < 2; ++ks) {
#pragma unroll
    for (int si = 0; si < NT; ++si) {
      int kt = start + si;
      bf16x8 a = __builtin_bit_cast(bf16x8,
          *(const u16x8*)&Ks[(kt * 16 + l15) * KPAD + ks * 32 + quad * 8]);
      S[si] = __builtin_amdgcn_mfma_f32_16x16x32_bf16(a, qfrag[ks], S[si], 0, 0, 0);
    }
  }

  // ---- mask + row max. band: key in (lq, lq+128]; start-clip only for j==0 ----
  const int minkey = (j == 0) ? NEIGH_ : 0;
  float m = -1e30f;
#pragma unroll
  for (int si = 0; si < NT; ++si) {
#pragma unroll
    for (int r = 0; r < 4; ++r) {
      int key = (start + si) * 16 + quad * 4 + r;
      bool valid = ((u32)(key - lq - 1) < 128u) & (key >= minkey);
      float s = valid ? S[si][r] : -1e30f;
      S[si][r] = s;
      m = fmaxf(m, s);
    }
  }
  m = fmaxf(m, __shfl_xor(m, 16));
  m = fmaxf(m, __shfl_xor(m, 32));

  // ---- exp2 + row sum; pack P to bf16 pairs (C-layout regs (0,1),(2,3)) ----
  float lsum = 0.f;
  u32 pk[NT][2];
#pragma unroll
  for (int si = 0; si < NT; ++si) {
    float p0 = exp2f(S[si][0] - m);
    float p1 = exp2f(S[si][1] - m);
    float p2 = exp2f(S[si][2] - m);
    float p3 = exp2f(S[si][3] - m);
    lsum += (p0 + p1) + (p2 + p3);
    pk[si][0] = pack2(p0, p1);
    pk[si][1] = pack2(p2, p3);
  }
  lsum += __shfl_xor(lsum, 16);
  lsum += __shfl_xor(lsum, 32);
  const float inv = 1.0f / lsum;

  // ---- T14 issue-early: V global loads in flight across barrier 2 ----
  float4 vA[4], vB[4];
#pragma unroll
  for (int i = 0; i < 4; ++i) {
    int idx = t + i * 512;                 // 0..2047
    int kp = idx >> 4, c4 = idx & 15;      // key pair 0..127, col group 0..15
    int k0g = g0 + 2 * kp, k1g = k0g + 1;
    k0g = k0g < 0 ? 0 : k0g; k1g = k1g < 0 ? 0 : k1g;
    vA[i] = *(const float4*)(V + ((((size_t)b * L_) + k0g) * H_ + h) * E_ + c4 * 4);
    vB[i] = *(const float4*)(V + ((((size_t)b * L_) + k1g) * H_ + h) * E_ + c4 * 4);
  }

  __syncthreads();   // barrier 2: all Ks reads done; LDS may be overwritten

  // ---- write V^T [e][key] (XOR-swizzled 8-key groups) into the SAME buffer ----
#pragma unroll
  for (int i = 0; i < 4; ++i) {
    int idx = t + i * 512;
    int kp = idx >> 4, c4 = idx & 15;
    int g = kp >> 2;                       // 8-key group 0..31
    int ko = kp & 3;                       // u32 offset within group
    const float a0[4] = {vA[i].x, vA[i].y, vA[i].z, vA[i].w};
    const float a1[4] = {vB[i].x, vB[i].y, vB[i].z, vB[i].w};
#pragma unroll
    for (int w = 0; w < 4; ++w) {
      int e = c4 * 4 + w;
      int gs = g ^ (e & 31);               // swizzled group
      Vs32[e * 128 + gs * 4 + ko] = pack2(a0[w], a1[w]);
    }
  }
  __syncthreads();   // barrier 3: Vs staged

  // ---- O = P V : A = P via register transpose (shfl), B = VsT swizzled ----
  f32x4 O[4];
#pragma unroll
  for (int et = 0; et < 4; ++et) O[et] = (f32x4){0.f, 0.f, 0.f, 0.f};
  const int srcBase = 16 * ((quad & 1) * 2) + l15;   // + 16*(k>>1)
  const bool hiTile = (quad >> 1) != 0;
#pragma unroll
  for (int pi = 0; pi < NP; ++pi) {
    const int ap = ks0 + pi;               // absolute 32-key chunk
    u32 a32[4];
#pragma unroll
    for (int k = 0; k < 4; ++k) {
      int src = srcBase + 16 * (k >> 1);
      u32 u0 = (u32)__shfl((int)pk[2 * pi][k & 1], src);
      u32 u1 = (u32)__shfl((int)pk[2 * pi + 1][k & 1], src);
      a32[k] = hiTile ? u1 : u0;
    }
    bf16x8 afrag = __builtin_bit_cast(bf16x8,
        (u32x4){a32[0], a32[1], a32[2], a32[3]});
    __builtin_amdgcn_s_setprio(1);
#pragma unroll
    for (int et = 0; et < 4; ++et) {
      int e = et * 16 + l15;
      int gs = (ap * 4 + quad) ^ (e & 31);
      bf16x8 bfrag = __builtin_bit_cast(bf16x8,
          *(const u16x8*)((const unsigned short*)Vs32 + e * 256 + gs * 8));
      O[et] = __builtin_amdgcn_mfma_f32_16x16x32_bf16(afrag, bfrag, O[et], 0, 0, 0);
    }
    __builtin_amdgcn_s_setprio(0);
  }

  // ---- store: O C-layout row = q = quad*4+r, col = e = et*16+l15 ----
  float invq[4];
#pragma unroll
  for (int r = 0; r < 4; ++r) invq[r] = __shfl(inv, quad * 4 + r);
#pragma unroll
  for (int et = 0; et < 4; ++et)
#pragma unroll
    for (int r = 0; r < 4; ++r) {
      int row = r0 + quad * 4 + r;
      out[((((size_t)b * L_) + q0 + row) * H_ + h) * E_ + et * 16 + l15] = O[et][r] * invq[r];
    }
}

extern "C" void kernel_launch(void* const* d_in, const int* in_sizes, int n_in,
                              void* d_out, int out_size, void* d_ws, size_t ws_size,
                              hipStream_t stream) {
  const float* q = (const float*)d_in[0];
  const float* k = (const float*)d_in[1];
  const float* v = (const float*)d_in[2];
  float* o = (float*)d_out;
  dim3 grid(SPLITS_, H_, B_);   // 2048 blocks
  la_kernel<<<grid, 512, 0, stream>>>(q, k, v, o);
}